// Round 2
// baseline (801.610 us; speedup 1.0000x reference)
//
#include <hip/hip_runtime.h>
#include <hip/hip_bf16.h>

// DiffRenderer: softmax over 69 chars per (384x768) cell, blend 28x14 font
// tiles, assemble (10752,10752) image. Inputs f32, OUTPUT f32 (jax default —
// round-1 failure was writing bf16 into a float* buffer).
#define ROWS 384
#define COLS 768
#define NCH  69
#define CH   28
#define CW   14
#define IMG_W (COLS * CW)   // 10752
#define TPB  256            // cells per block (768 cols = 3 blocks/row)

__global__ __launch_bounds__(TPB)
void diffrender_kernel(const float* __restrict__ logits,   // (384,768,69) f32
                       const float* __restrict__ font,     // (69,28,14)  f32
                       float* __restrict__ out)            // (10752,10752) f32
{
    __shared__ float stage[TPB * CW];  // 14 KB row-segment staging

    const int tid  = threadIdx.x;
    const int cell = blockIdx.x * TPB + tid;
    const int r    = blockIdx.x / 3;             // cell row (block-uniform)
    const int c0   = (blockIdx.x % 3) * TPB;     // first cell col of block

    // ---- per-thread softmax over 69 logits, probs kept in registers ----
    const float* lp = logits + (size_t)cell * NCH;
    float e[NCH];
    float m = -INFINITY;
#pragma unroll
    for (int n = 0; n < NCH; ++n) {
        e[n] = lp[n];
        m = fmaxf(m, e[n]);
    }
    float s = 0.f;
#pragma unroll
    for (int n = 0; n < NCH; ++n) {
        e[n] = __expf(e[n] - m);
        s += e[n];
    }
    const float inv = 1.f / s;
#pragma unroll
    for (int n = 0; n < NCH; ++n) e[n] *= inv;

    // ---- blend + assemble, one image row (within the tile) at a time ----
    for (int h = 0; h < CH; ++h) {
        float acc[CW];
#pragma unroll
        for (int w = 0; w < CW; ++w) acc[w] = 0.f;

        const float* fp = font + h * CW;         // wave-uniform address
#pragma unroll
        for (int n = 0; n < NCH; ++n) {
#pragma unroll
            for (int w = 0; w < CW; ++w) {
                acc[w] = fmaf(e[n], fp[n * (CH * CW) + w], acc[w]);
            }
        }

        // stage to LDS, then coalesced float2 stores of the 3584-px segment
#pragma unroll
        for (int w = 0; w < CW; ++w) stage[tid * CW + w] = acc[w];
        __syncthreads();

        const size_t rowbase = (size_t)(r * CH + h) * IMG_W + (size_t)c0 * CW;
        const float2* st2 = (const float2*)stage;          // 1792 float2
        float2* o2 = (float2*)(out + rowbase);             // rowbase is even
#pragma unroll
        for (int k = 0; k < 7; ++k) {
            o2[k * TPB + tid] = st2[k * TPB + tid];
        }
        __syncthreads();  // protect stage[] before next h
    }
}

extern "C" void kernel_launch(void* const* d_in, const int* in_sizes, int n_in,
                              void* d_out, int out_size, void* d_ws, size_t ws_size,
                              hipStream_t stream) {
    const float* logits = (const float*)d_in[0];   // (384,768,69) f32
    const float* font   = (const float*)d_in[1];   // (69,28,14)  f32
    float* out          = (float*)d_out;           // (10752,10752) f32

    const int n_cells = ROWS * COLS;               // 294912
    const int blocks  = n_cells / TPB;             // 1152
    diffrender_kernel<<<blocks, TPB, 0, stream>>>(logits, font, out);
}

// Round 3
// 674.204 us; speedup vs baseline: 1.1890x; 1.1890x over previous
//
#include <hip/hip_runtime.h>
#include <hip/hip_bf16.h>

// DiffRenderer v3: softmax(69) per cell -> blend 28x14 font tiles -> (10752,10752) f32.
// Round-2 post-mortem: VALUBusy 9.6% == exactly the fp32 FMA floor smeared over 8x
// stall time (barriers + per-row font load latency + grid imbalance). This version:
// 1-wave workgroups (no barriers), acc = one image row (14 f32), probs packed bf16
// in 35 VGPRs, font loads wave-uniform affine (scalarizable), direct float2 stores.
#define ROWS 384
#define COLS 768
#define NCH  69
#define CH   28
#define CW   14
#define IMG_W (COLS * CW)   // 10752

__device__ __forceinline__ unsigned bf16bits(float x) {
    unsigned b = __float_as_uint(x);
    b += 0x7FFFu + ((b >> 16) & 1u);   // round-to-nearest-even
    return b >> 16;
}

__global__ __launch_bounds__(64)
void diffrender_v3(const float* __restrict__ logits,   // (384,768,69) f32
                   const float* __restrict__ font,     // (69,28,14)  f32
                   float* __restrict__ out)            // (10752,10752) f32
{
    const int lane = threadIdx.x;
    const int cell = blockIdx.x * 64 + lane;           // 294912 cells
    const int r    = cell / COLS;                      // uniform within wg (768=12*64)
    const int c    = cell % COLS;

    // ---- softmax over 69 logits (per-thread, registers) ----
    const float* lp = logits + (size_t)cell * NCH;
    float e[NCH];
    float m = -INFINITY;
#pragma unroll
    for (int n = 0; n < NCH; ++n) { e[n] = lp[n]; m = fmaxf(m, e[n]); }
    float s = 0.f;
#pragma unroll
    for (int n = 0; n < NCH; ++n) { e[n] = __expf(e[n] - m); s += e[n]; }
    const float inv = 1.f / s;

    // ---- pack probs to bf16 pairs: 35 VGPRs hold all 69 ----
    unsigned pk[(NCH + 1) / 2];
#pragma unroll
    for (int i = 0; i < NCH / 2; ++i) {
        unsigned lo = bf16bits(e[2 * i] * inv);
        unsigned hi = bf16bits(e[2 * i + 1] * inv);
        pk[i] = lo | (hi << 16);
    }
    pk[NCH / 2] = bf16bits(e[NCH - 1] * inv);          // n=68, low half

    // ---- blend: one image row at a time, acc[14] only ----
    for (int hh = 0; hh < CH; ++hh) {
        float2 acc[CW / 2];
#pragma unroll
        for (int w = 0; w < CW / 2; ++w) acc[w] = make_float2(0.f, 0.f);

        const float* fh = font + hh * CW;              // + n*(CH*CW), uniform
#pragma unroll
        for (int n = 0; n < NCH; ++n) {
            const float p = (n & 1) ? __uint_as_float(pk[n >> 1] & 0xFFFF0000u)
                                    : __uint_as_float(pk[n >> 1] << 16);
            const float2* f2 = (const float2*)(fh + n * (CH * CW)); // 8B-aligned
#pragma unroll
            for (int w = 0; w < CW / 2; ++w) {
                const float2 fv = f2[w];               // wave-uniform value
                acc[w].x = fmaf(p, fv.x, acc[w].x);
                acc[w].y = fmaf(p, fv.y, acc[w].y);
            }
        }

        // direct stores: wave covers a contiguous 3584B span per w-step
        float2* o2 = (float2*)(out + (size_t)(r * CH + hh) * IMG_W + (size_t)c * CW);
#pragma unroll
        for (int w = 0; w < CW / 2; ++w) o2[w] = acc[w];
    }
}

extern "C" void kernel_launch(void* const* d_in, const int* in_sizes, int n_in,
                              void* d_out, int out_size, void* d_ws, size_t ws_size,
                              hipStream_t stream) {
    const float* logits = (const float*)d_in[0];   // (384,768,69) f32
    const float* font   = (const float*)d_in[1];   // (69,28,14)  f32
    float* out          = (float*)d_out;           // (10752,10752) f32

    const int n_cells = ROWS * COLS;               // 294912
    const int blocks  = n_cells / 64;              // 4608 one-wave workgroups
    diffrender_v3<<<blocks, 64, 0, stream>>>(logits, font, out);
}

// Round 4
// 164.571 us; speedup vs baseline: 4.8709x; 4.0967x over previous
//
#include <hip/hip_runtime.h>
#include <hip/hip_bf16.h>

// DiffRenderer v4: reformulated as bf16-MFMA GEMM.
//   P(294912 cells x 69 chars) . F(69 chars x 392 px) -> image (10752^2 f32).
// Round-3 post-mortem: VALU-issue was pinned at the 106us fp32-FMA floor with
// 8x stall (uniform font loads on the critical path, 29% occupancy). MFMA
// moves the FLOPs to the matrix pipe -> memory-bound (~90us floor).
// Structure = m97-verified B^T GEMM: A-frag/B-frag = 8 contiguous k per lane.
#define ROWS 384
#define COLS 768
#define NCH  69
#define CH   28
#define CW   14
#define NPX  392            // CH*CW
#define KP   96             // K padded to 3 MFMA k-steps of 32
#define PXP  400            // px padded to 25 tiles of 16
#define IMG_W 10752
#define PA_PAD 104          // LDS row pad (bf16): 208B stride -> 2-way banks

typedef __attribute__((ext_vector_type(8))) short bfrag;   // 8 bf16 (4 VGPR)
typedef __attribute__((ext_vector_type(4))) float f32x4;   // C/D frag

__device__ __forceinline__ unsigned bf16bits(float x) {
    unsigned b = __float_as_uint(x);
    b += 0x7FFFu + ((b >> 16) & 1u);   // RTNE
    return b >> 16;
}

// ---- kernel 1: font (69,28,14) f32 -> Ft[400][96] bf16 (transposed, padded) ----
__global__ __launch_bounds__(256)
void font_transpose(const float* __restrict__ font, unsigned short* __restrict__ Ft) {
    int idx = blockIdx.x * 256 + threadIdx.x;        // 0..38399
    if (idx >= PXP * KP) return;
    int px = idx / KP, k = idx % KP;
    float v = (px < NPX && k < NCH) ? font[k * NPX + px] : 0.f;
    Ft[idx] = (unsigned short)bf16bits(v);
}

// ---- kernel 2: softmax + MFMA blend + assemble ----
__global__ __launch_bounds__(256)
void diffrender_mfma(const float* __restrict__ logits,       // (294912,69) f32
                     const unsigned short* __restrict__ Ft,  // (400,96) bf16
                     float* __restrict__ out)                // (10752,10752) f32
{
    __shared__ __align__(16) unsigned short Pa[256][PA_PAD]; // 53.2 KB

    const int tid  = threadIdx.x;
    const int lane = tid & 63;
    const int wv   = tid >> 6;                  // wave 0..3
    const int cellbase = blockIdx.x * 256;
    const int r    = blockIdx.x / 3;            // cell row (uniform)
    const int cb   = (blockIdx.x % 3) * 256;    // first cell col of block

    // ---- per-thread softmax over 69 logits ----
    const float* lp = logits + (size_t)(cellbase + tid) * NCH;
    float e[NCH];
    float m = -INFINITY;
#pragma unroll
    for (int n = 0; n < NCH; ++n) { e[n] = lp[n]; m = fmaxf(m, e[n]); }
    float s = 0.f;
#pragma unroll
    for (int n = 0; n < NCH; ++n) { e[n] = __expf(e[n] - m); s += e[n]; }
    const float inv = 1.f / s;

    // ---- pack probs bf16 -> LDS row tid (k 0..95, zero-padded past 68) ----
    unsigned* prow = (unsigned*)&Pa[tid][0];
#pragma unroll
    for (int i = 0; i < 34; ++i)
        prow[i] = bf16bits(e[2 * i] * inv) | (bf16bits(e[2 * i + 1] * inv) << 16);
    prow[34] = bf16bits(e[68] * inv);           // k=68 | 0
#pragma unroll
    for (int i = 35; i < 48; ++i) prow[i] = 0;  // k 70..95 = 0
    __syncthreads();

    // ---- load this wave's 12 A-fragments (4 M-tiles x 3 k-steps) ----
    const int arow = (lane & 15);               // row within 16-cell tile
    const int kgrp = (lane >> 4) * 8;           // k-slice base within k-step
    bfrag a[4][3];
#pragma unroll
    for (int mt = 0; mt < 4; ++mt)
#pragma unroll
        for (int ks = 0; ks < 3; ++ks)
            a[mt][ks] = *(const bfrag*)&Pa[wv * 64 + mt * 16 + arow][ks * 32 + kgrp];

    // ---- px-tile loop: 25 tiles of 16 px, software-pipelined B loads ----
    const int pxl = lane & 15;                  // px within tile (= D col)
    const int crow4 = (lane >> 4) * 4;          // first D row of this lane
    bfrag bcur[3], bnxt[3];
#pragma unroll
    for (int ks = 0; ks < 3; ++ks)
        bcur[ks] = *(const bfrag*)&Ft[(size_t)pxl * KP + ks * 32 + kgrp];

    for (int pt = 0; pt < 25; ++pt) {
        if (pt < 24) {
            const size_t pb = (size_t)((pt + 1) * 16 + pxl) * KP + kgrp;
#pragma unroll
            for (int ks = 0; ks < 3; ++ks)
                bnxt[ks] = *(const bfrag*)&Ft[pb + ks * 32];
        }

        f32x4 acc[4] = {f32x4{0,0,0,0}, f32x4{0,0,0,0}, f32x4{0,0,0,0}, f32x4{0,0,0,0}};
#pragma unroll
        for (int mt = 0; mt < 4; ++mt)
#pragma unroll
            for (int ks = 0; ks < 3; ++ks)
                acc[mt] = __builtin_amdgcn_mfma_f32_16x16x32_bf16(a[mt][ks], bcur[ks], acc[mt], 0, 0, 0);

        // ---- store: px -> (h,w); cell -> (r, c) ----
        const int px = pt * 16 + pxl;
        const int h  = px / CW;                 // magic-mul div
        const int w  = px - h * CW;
        const bool pxok = (px < NPX);
        const size_t rowbase = (size_t)(r * CH + h) * IMG_W + w;
#pragma unroll
        for (int mt = 0; mt < 4; ++mt) {
#pragma unroll
            for (int j = 0; j < 4; ++j) {
                const int c = cb + wv * 64 + mt * 16 + crow4 + j;
                if (pxok) out[rowbase + (size_t)c * CW] = acc[mt][j];
            }
        }
#pragma unroll
        for (int ks = 0; ks < 3; ++ks) bcur[ks] = bnxt[ks];
    }
}

extern "C" void kernel_launch(void* const* d_in, const int* in_sizes, int n_in,
                              void* d_out, int out_size, void* d_ws, size_t ws_size,
                              hipStream_t stream) {
    const float* logits = (const float*)d_in[0];   // (384,768,69) f32
    const float* font   = (const float*)d_in[1];   // (69,28,14)  f32
    float* out          = (float*)d_out;           // (10752,10752) f32
    unsigned short* Ft  = (unsigned short*)d_ws;   // (400,96) bf16 = 76.8 KB

    font_transpose<<<(PXP * KP + 255) / 256, 256, 0, stream>>>(font, Ft);

    const int blocks = (ROWS * COLS) / 256;        // 1152
    diffrender_mfma<<<blocks, 256, 0, stream>>>(logits, Ft, out);
}

// Round 5
// 124.035 us; speedup vs baseline: 6.4628x; 1.3268x over previous
//
#include <hip/hip_runtime.h>
#include <hip/hip_bf16.h>

// DiffRenderer v5: bf16-MFMA GEMM, image-row-major N-tiles, barrier-free.
// Round-4 post-mortem: 164us vs 86us memory floor; gap attributed to 400
// scattered 4B stores/lane (56B-stride, ~10 lines/inst in the TA).
// v5: font as Fh[28][16][96] (one h-row per MFMA N-tile, 14 valid + 2 zero
// cols); per-wave LDS transpose of the 64-cell x 14-px result; 7 coalesced
// float2 stores per image row per wave. No __syncthreads anywhere: probs
// staging + output transpose live in per-wave LDS regions ordered by
// s_waitcnt lgkmcnt(0) fences (stage overlays the dead prob buffer).
#define ROWS 384
#define COLS 768
#define NCH  69
#define CH   28
#define CW   14
#define KP   96             // K padded to 3 MFMA k-steps of 32
#define IMG_W 10752
#define ROW_U 104           // prob-row stride in ushorts (208B, 16B-aligned)

typedef __attribute__((ext_vector_type(8))) short bfrag;   // 8 bf16 (4 VGPR)
typedef __attribute__((ext_vector_type(4))) float f32x4;   // C/D frag

__device__ __forceinline__ unsigned bf16bits(float x) {
    unsigned b = __float_as_uint(x);
    b += 0x7FFFu + ((b >> 16) & 1u);   // RTNE
    return b >> 16;
}

__device__ __forceinline__ void lds_fence() {
    // order per-wave LDS write->read phases; also a compiler memory fence
    asm volatile("s_waitcnt lgkmcnt(0)" ::: "memory");
}

// ---- kernel 1: font (69,28,14) f32 -> Fh[28][16][96] bf16 ----
__global__ __launch_bounds__(256)
void font_prep(const float* __restrict__ font, unsigned short* __restrict__ Fh) {
    int idx = blockIdx.x * 256 + threadIdx.x;        // 28*16*96 = 43008
    if (idx >= CH * 16 * KP) return;
    int k  = idx % KP;
    int hw = idx / KP;
    int w  = hw % 16, h = hw / 16;
    float v = (w < CW && k < NCH) ? font[k * (CH * CW) + h * CW + w] : 0.f;
    Fh[idx] = (unsigned short)bf16bits(v);
}

// ---- kernel 2: softmax + MFMA blend + row-coalesced assemble ----
__global__ __launch_bounds__(128)
void diffrender_v5(const float* __restrict__ logits,       // (294912,69) f32
                   const unsigned short* __restrict__ Fh,  // (28,16,96) bf16
                   float* __restrict__ out)                // (10752,10752) f32
{
    __shared__ __align__(16) unsigned short smem[2][64 * ROW_U]; // 26.6KB, per-wave

    const int tid  = threadIdx.x;
    const int lane = tid & 63;
    const int wv   = tid >> 6;
    const int cell = blockIdx.x * 128 + tid;         // row-major over (384,768)
    const int r    = blockIdx.x / 6;                 // cell row (6 blocks/row)
    const int cb   = (blockIdx.x % 6) * 128;         // first cell col of block

    // ---- per-thread softmax over 69 logits ----
    const float* lp = logits + (size_t)cell * NCH;
    float e[NCH];
    float m = -INFINITY;
#pragma unroll
    for (int n = 0; n < NCH; ++n) { e[n] = lp[n]; m = fmaxf(m, e[n]); }
    float s = 0.f;
#pragma unroll
    for (int n = 0; n < NCH; ++n) { e[n] = __expf(e[n] - m); s += e[n]; }
    const float inv = 1.f / s;

    // ---- pack probs bf16 -> per-wave LDS row (k 0..95, zero-padded) ----
    unsigned* prow = (unsigned*)&smem[wv][(size_t)lane * ROW_U];
#pragma unroll
    for (int i = 0; i < 34; ++i)
        prow[i] = bf16bits(e[2 * i] * inv) | (bf16bits(e[2 * i + 1] * inv) << 16);
    prow[34] = bf16bits(e[68] * inv);
#pragma unroll
    for (int i = 35; i < 48; ++i) prow[i] = 0;
    lds_fence();

    // ---- this wave's 12 A-fragments (4 M-tiles x 3 k-steps) ----
    const int w15   = lane & 15;
    const int kgrp  = (lane >> 4) * 8;
    const int crow4 = (lane >> 4) * 4;
    bfrag a[4][3];
#pragma unroll
    for (int mt = 0; mt < 4; ++mt)
#pragma unroll
        for (int ks = 0; ks < 3; ++ks)
            a[mt][ks] = *(const bfrag*)&smem[wv][(size_t)(mt * 16 + w15) * ROW_U + ks * 32 + kgrp];
    lds_fence();  // a-frags in regs; prob buffer now dead -> reuse as stage

    float* stage = (float*)&smem[wv][0];             // 64 cells x 14 px f32

    // ---- h loop: one image row per iteration, double-buffered B ----
    const unsigned short* fb = Fh + (size_t)w15 * KP + kgrp;
    bfrag bcur[3], bnxt[3];
#pragma unroll
    for (int ks = 0; ks < 3; ++ks)
        bcur[ks] = *(const bfrag*)(fb + ks * 32);

    for (int h = 0; h < CH; ++h) {
        if (h + 1 < CH) {
            const unsigned short* fn = fb + (size_t)(h + 1) * 16 * KP;
#pragma unroll
            for (int ks = 0; ks < 3; ++ks)
                bnxt[ks] = *(const bfrag*)(fn + ks * 32);
        }

        f32x4 acc[4] = {f32x4{0,0,0,0}, f32x4{0,0,0,0}, f32x4{0,0,0,0}, f32x4{0,0,0,0}};
#pragma unroll
        for (int mt = 0; mt < 4; ++mt)
#pragma unroll
            for (int ks = 0; ks < 3; ++ks)
                acc[mt] = __builtin_amdgcn_mfma_f32_16x16x32_bf16(a[mt][ks], bcur[ks], acc[mt], 0, 0, 0);

        // transpose through per-wave LDS: D[row=cell_local][col=w]
        if (w15 < CW) {
#pragma unroll
            for (int mt = 0; mt < 4; ++mt)
#pragma unroll
                for (int j = 0; j < 4; ++j)
                    stage[(mt * 16 + crow4 + j) * CW + w15] = acc[mt][j];
        }
        lds_fence();

        // coalesced stores: wave's 64 cells x 14 px = 3584B contiguous span
        float2* o2 = (float2*)(out + (size_t)(r * CH + h) * IMG_W + (size_t)(cb + wv * 64) * CW);
        const float2* s2 = (const float2*)stage;
#pragma unroll
        for (int i = 0; i < 7; ++i)
            o2[i * 64 + lane] = s2[i * 64 + lane];
        lds_fence();  // reads done before next iteration's stage writes

#pragma unroll
        for (int ks = 0; ks < 3; ++ks) bcur[ks] = bnxt[ks];
    }
}

extern "C" void kernel_launch(void* const* d_in, const int* in_sizes, int n_in,
                              void* d_out, int out_size, void* d_ws, size_t ws_size,
                              hipStream_t stream) {
    const float* logits = (const float*)d_in[0];   // (384,768,69) f32
    const float* font   = (const float*)d_in[1];   // (69,28,14)  f32
    float* out          = (float*)d_out;           // (10752,10752) f32
    unsigned short* Fh  = (unsigned short*)d_ws;   // (28,16,96) bf16 = 86KB

    font_prep<<<(CH * 16 * KP + 255) / 256, 256, 0, stream>>>(font, Fh);

    const int blocks = (ROWS * COLS) / 128;        // 2304
    diffrender_v5<<<blocks, 128, 0, stream>>>(logits, Fh, out);
}

// Round 6
// 121.990 us; speedup vs baseline: 6.5711x; 1.0168x over previous
//
#include <hip/hip_runtime.h>
#include <hip/hip_bf16.h>

// DiffRenderer v6: bf16-MFMA GEMM, image-row-major N-tiles, barrier-free.
// Round-5 post-mortem: 124us vs ~78us write-dominated floor; biggest per-wave
// cost was 56 explicit full lgkmcnt(0) drains (~8k cyc/wave). v6 removes ALL
// explicit fences (wave-private LDS; compiler emits counted lgkmcnt and can
// overlap stage-reads with MFMA), processes 2 image rows per iteration
// (14 wait points), and stores via masked float4 (4 insts/row vs 7 float2).
#define ROWS 384
#define COLS 768
#define NCH  69
#define CH   28
#define CW   14
#define KP   96             // K padded to 3 MFMA k-steps of 32
#define IMG_W 10752
#define ROW_U 104           // prob-row stride in ushorts (208B, 16B-aligned)

typedef __attribute__((ext_vector_type(8))) short bfrag;   // 8 bf16 (4 VGPR)
typedef __attribute__((ext_vector_type(4))) float f32x4;   // C/D frag

__device__ __forceinline__ unsigned bf16bits(float x) {
    unsigned b = __float_as_uint(x);
    b += 0x7FFFu + ((b >> 16) & 1u);   // RTNE
    return b >> 16;
}

// ---- kernel 1: font (69,28,14) f32 -> Fh[28][16][96] bf16 ----
__global__ __launch_bounds__(256)
void font_prep(const float* __restrict__ font, unsigned short* __restrict__ Fh) {
    int idx = blockIdx.x * 256 + threadIdx.x;        // 28*16*96 = 43008
    if (idx >= CH * 16 * KP) return;
    int k  = idx % KP;
    int hw = idx / KP;
    int w  = hw % 16, h = hw / 16;
    float v = (w < CW && k < NCH) ? font[k * (CH * CW) + h * CW + w] : 0.f;
    Fh[idx] = (unsigned short)bf16bits(v);
}

// ---- kernel 2: softmax + MFMA blend + row-coalesced assemble ----
__global__ __launch_bounds__(128, 3)
void diffrender_v6(const float* __restrict__ logits,       // (294912,69) f32
                   const unsigned short* __restrict__ Fh,  // (28,16,96) bf16
                   float* __restrict__ out)                // (10752,10752) f32
{
    __shared__ __align__(16) unsigned short smem[2][64 * ROW_U]; // 26.6KB, per-wave

    const int tid  = threadIdx.x;
    const int lane = tid & 63;
    const int wv   = tid >> 6;
    const int cell = blockIdx.x * 128 + tid;         // row-major over (384,768)
    const int r    = blockIdx.x / 6;                 // cell row (6 blocks/row)
    const int cb   = (blockIdx.x % 6) * 128;         // first cell col of block

    // ---- per-thread softmax over 69 logits ----
    const float* lp = logits + (size_t)cell * NCH;
    float e[NCH];
    float m = -INFINITY;
#pragma unroll
    for (int n = 0; n < NCH; ++n) { e[n] = lp[n]; m = fmaxf(m, e[n]); }
    float s = 0.f;
#pragma unroll
    for (int n = 0; n < NCH; ++n) { e[n] = __expf(e[n] - m); s += e[n]; }
    const float inv = 1.f / s;

    // ---- pack probs bf16 -> per-wave LDS row (k 0..95, zero-padded) ----
    // Compiler sees these LDS writes and the A-frag reads below in program
    // order on the same object -> emits the needed counted lgkmcnt itself.
    unsigned* prow = (unsigned*)&smem[wv][(size_t)lane * ROW_U];
#pragma unroll
    for (int i = 0; i < 34; ++i)
        prow[i] = bf16bits(e[2 * i] * inv) | (bf16bits(e[2 * i + 1] * inv) << 16);
    prow[34] = bf16bits(e[68] * inv);
#pragma unroll
    for (int i = 35; i < 48; ++i) prow[i] = 0;

    // ---- this wave's 12 A-fragments (4 M-tiles x 3 k-steps) ----
    const int w15   = lane & 15;
    const int kgrp  = (lane >> 4) * 8;
    const int crow4 = (lane >> 4) * 4;
    bfrag a[4][3];
#pragma unroll
    for (int mt = 0; mt < 4; ++mt)
#pragma unroll
        for (int ks = 0; ks < 3; ++ks)
            a[mt][ks] = *(const bfrag*)&smem[wv][(size_t)(mt * 16 + w15) * ROW_U + ks * 32 + kgrp];

    // prob buffer dead after a-frag reads -> reuse as f32 stage (2 rows x 896)
    float* stage = (float*)&smem[wv][0];

    // ---- h loop: TWO image rows per iteration, double-buffered B ----
    const unsigned short* fb = Fh + (size_t)w15 * KP + kgrp;
    bfrag bcur[2][3], bnxt[2][3];
#pragma unroll
    for (int hh = 0; hh < 2; ++hh)
#pragma unroll
        for (int ks = 0; ks < 3; ++ks)
            bcur[hh][ks] = *(const bfrag*)(fb + (size_t)(hh * 16) * KP + ks * 32);

#pragma unroll 1
    for (int h2 = 0; h2 < CH / 2; ++h2) {
        const int h = 2 * h2;
        if (h2 + 1 < CH / 2) {
            const unsigned short* fn = fb + (size_t)((h + 2) * 16) * KP;
#pragma unroll
            for (int hh = 0; hh < 2; ++hh)
#pragma unroll
                for (int ks = 0; ks < 3; ++ks)
                    bnxt[hh][ks] = *(const bfrag*)(fn + (size_t)(hh * 16) * KP + ks * 32);
        }

        f32x4 acc[2][4];
#pragma unroll
        for (int hh = 0; hh < 2; ++hh)
#pragma unroll
            for (int mt = 0; mt < 4; ++mt)
                acc[hh][mt] = f32x4{0, 0, 0, 0};
#pragma unroll
        for (int hh = 0; hh < 2; ++hh)
#pragma unroll
            for (int mt = 0; mt < 4; ++mt)
#pragma unroll
                for (int ks = 0; ks < 3; ++ks)
                    acc[hh][mt] = __builtin_amdgcn_mfma_f32_16x16x32_bf16(
                        a[mt][ks], bcur[hh][ks], acc[hh][mt], 0, 0, 0);

        // transpose through per-wave LDS: stage[hh][cell_local*14 + w]
        if (w15 < CW) {
#pragma unroll
            for (int hh = 0; hh < 2; ++hh)
#pragma unroll
                for (int mt = 0; mt < 4; ++mt)
#pragma unroll
                    for (int j = 0; j < 4; ++j)
                        stage[hh * 896 + (mt * 16 + crow4 + j) * CW + w15] = acc[hh][mt][j];
        }

        // coalesced stores: per row, 896 floats = 224 float4 (4 masked insts)
#pragma unroll
        for (int hh = 0; hh < 2; ++hh) {
            float4* o4 = (float4*)(out + (size_t)(r * CH + h + hh) * IMG_W
                                       + (size_t)(cb + wv * 64) * CW);
            const float4* s4 = (const float4*)(stage + hh * 896);
#pragma unroll
            for (int i = 0; i < 4; ++i) {
                const int idx = i * 64 + lane;
                if (idx < 224) o4[idx] = s4[idx];
            }
        }

#pragma unroll
        for (int hh = 0; hh < 2; ++hh)
#pragma unroll
            for (int ks = 0; ks < 3; ++ks)
                bcur[hh][ks] = bnxt[hh][ks];
    }
}

extern "C" void kernel_launch(void* const* d_in, const int* in_sizes, int n_in,
                              void* d_out, int out_size, void* d_ws, size_t ws_size,
                              hipStream_t stream) {
    const float* logits = (const float*)d_in[0];   // (384,768,69) f32
    const float* font   = (const float*)d_in[1];   // (69,28,14)  f32
    float* out          = (float*)d_out;           // (10752,10752) f32
    unsigned short* Fh  = (unsigned short*)d_ws;   // (28,16,96) bf16 = 86KB

    font_prep<<<(CH * 16 * KP + 255) / 256, 256, 0, stream>>>(font, Fh);

    const int blocks = (ROWS * COLS) / 128;        // 2304
    diffrender_v6<<<blocks, 128, 0, stream>>>(logits, Fh, out);
}